// Round 9
// baseline (129.636 us; speedup 1.0000x reference)
//
#include <hip/hip_runtime.h>
#include <hip/hip_bf16.h>

#define NB 4096
#define DK 1024           // elements per row (fp8 row = 1024 B)
#define EPSF 1e-6f
#define QSCALE 16.0f      // fp8 pre-scale (power of 2; cancelled exactly in exp)

typedef __attribute__((ext_vector_type(8))) int   i32x8_t;
typedef __attribute__((ext_vector_type(4))) int   i32x4_t;
typedef __attribute__((ext_vector_type(4))) float f32x4_t;

// ---------------------------------------------------------------------------
// Fragment-swizzled fp8 layout (both matrices): for row, k:
//   p = row>>4, r = row&15, kb = k>>7, q = (k>>5)&3, b = k&31
//   byte offset = (p*32 + kb*4 + q)*512 + r*32 + b
// A wave's MFMA fragment (lane = q*16 + l15) for panel p, k-block kb is
// 64 lanes x 32 contiguous bytes at (p*32+kb*4+q)*512 + l15*32 — two
// coalesced global_load_dwordx4 per fragment. Bytes identical to the r5 LDS
// fragments (absmax-0 proven).
// ---------------------------------------------------------------------------

// ---------------------------------------------------------------------------
// Kernel 1: wave-per-row normalize of x and y -> fp8 e4m3 (x QSCALE) written
// in fragment-swizzled layout, plus exact fp32 diagonal cos-sim.
// (No accumulator zeroing needed anymore: r9 has no atomics; every partial
// slot is written unconditionally by the GEMM.)
// ---------------------------------------------------------------------------
__global__ __launch_bounds__(256) void normalize_rows(
    const float* __restrict__ x, const float* __restrict__ y,
    unsigned* __restrict__ xq, unsigned* __restrict__ yq,
    float* __restrict__ sdiag)
{
    const int t = threadIdx.x;
    const int wave = t >> 6;
    const int lane = t & 63;
    const int row  = blockIdx.x * 4 + wave;

    const float4* xr = reinterpret_cast<const float4*>(x + (size_t)row * DK);
    const float4* yr = reinterpret_cast<const float4*>(y + (size_t)row * DK);

    float4 xv[4], yv[4];
    float ssx = 0.f, ssy = 0.f, sxy = 0.f;
    #pragma unroll
    for (int j = 0; j < 4; ++j) {
        xv[j] = xr[j * 64 + lane];
        yv[j] = yr[j * 64 + lane];
        ssx += xv[j].x*xv[j].x + xv[j].y*xv[j].y + xv[j].z*xv[j].z + xv[j].w*xv[j].w;
        ssy += yv[j].x*yv[j].x + yv[j].y*yv[j].y + yv[j].z*yv[j].z + yv[j].w*yv[j].w;
        sxy += xv[j].x*yv[j].x + xv[j].y*yv[j].y + xv[j].z*yv[j].z + xv[j].w*yv[j].w;
    }
    #pragma unroll
    for (int off = 1; off < 64; off <<= 1) {
        ssx += __shfl_xor(ssx, off, 64);
        ssy += __shfl_xor(ssy, off, 64);
        sxy += __shfl_xor(sxy, off, 64);
    }
    const float invx = 1.0f / fmaxf(sqrtf(ssx), EPSF);
    const float invy = 1.0f / fmaxf(sqrtf(ssy), EPSF);
    const float sx = invx * QSCALE;
    const float sy = invy * QSCALE;

    // Swizzled destination for lane's float4 j (k0 = j*256 + lane*4):
    //   kb = j*2 + (lane>>5), q = (lane>>3)&3, b = (lane&7)*4
    const int p = row >> 4, r = row & 15;
    const int qs = (lane >> 3) & 3;
    const int bs = (lane & 7) * 4;
    #pragma unroll
    for (int j = 0; j < 4; ++j) {
        const int kb = j * 2 + (lane >> 5);
        const unsigned off = ((unsigned)(p * 32 + kb * 4 + qs) * 512 + r * 32 + bs) >> 2;
        int px = __builtin_amdgcn_cvt_pk_fp8_f32(xv[j].x * sx, xv[j].y * sx, 0, false);
        px     = __builtin_amdgcn_cvt_pk_fp8_f32(xv[j].z * sx, xv[j].w * sx, px, true);
        int py = __builtin_amdgcn_cvt_pk_fp8_f32(yv[j].x * sy, yv[j].y * sy, 0, false);
        py     = __builtin_amdgcn_cvt_pk_fp8_f32(yv[j].z * sy, yv[j].w * sy, py, true);
        xq[off] = (unsigned)px;
        yq[off] = (unsigned)py;
    }
    if (lane == 0) sdiag[row] = sxy * invx * invy;
}

// ---------------------------------------------------------------------------
// Kernel 2: S' = 256 * xn*yn^T via MX-fp8 (unit scales), 128x128 tiles.
// K-loop identical to r7 (no LDS, no barriers, direct swizzled-global
// fragments). NEW in r9: ZERO-ATOMIC epilogue. r2-r8 all funneled 524K
// device-scope atomicAdds onto 32 KB of accumulators (512 cache lines) —
// TCC RMW serialization ~30 us, the invariant "GEMM floor" that survived
// three different K-loop restructures. Now each wave plain-stores its
// shuffle-reduced partials to privatized slots:
//   rowpart[bx*2 + (wCol>>6)][row]  (64 slots/row, single writer each)
//   colpart[by*2 + (wRow>>6)][col]  (64 slots/col, single writer each)
// ---------------------------------------------------------------------------
__global__ __launch_bounds__(256) void gemm_exp_sums(
    const unsigned char* __restrict__ xq, const unsigned char* __restrict__ yq,
    float* __restrict__ rowpart, float* __restrict__ colpart)
{
    const int t    = threadIdx.x;
    const int lane = t & 63;
    const int wave = t >> 6;
    const int q    = lane >> 4;    // quad: selects 32B k-chunk
    const int l15  = lane & 15;

    const int R0 = blockIdx.y * 128;
    const int C0 = blockIdx.x * 128;
    const int wRow = (wave >> 1) * 64;   // wave's 64x64 quadrant
    const int wCol = (wave & 1) * 64;

    f32x4_t acc[4][4];
    #pragma unroll
    for (int i = 0; i < 4; i++)
        #pragma unroll
        for (int j = 0; j < 4; j++)
            acc[i][j] = (f32x4_t){0.f, 0.f, 0.f, 0.f};

    // Panel bases; mt/nt step = 32*512 = 16384 B, kb step = 4*512 = 2048 B.
    const unsigned char* Abase =
        xq + (size_t)(((R0 + wRow) >> 4) * 32 + q) * 512 + l15 * 32;
    const unsigned char* Bbase =
        yq + (size_t)(((C0 + wCol) >> 4) * 32 + q) * 512 + l15 * 32;

    #pragma unroll 1
    for (int kb = 0; kb < 8; ++kb) {
        const unsigned char* Ak = Abase + kb * 2048;
        const unsigned char* Bk = Bbase + kb * 2048;

        i32x8_t bfr[4];
        #pragma unroll
        for (int nt = 0; nt < 4; ++nt) {
            const i32x4_t lo = *reinterpret_cast<const i32x4_t*>(Bk + nt * 16384);
            const i32x4_t hi = *reinterpret_cast<const i32x4_t*>(Bk + nt * 16384 + 16);
            bfr[nt][0] = lo[0]; bfr[nt][1] = lo[1]; bfr[nt][2] = lo[2]; bfr[nt][3] = lo[3];
            bfr[nt][4] = hi[0]; bfr[nt][5] = hi[1]; bfr[nt][6] = hi[2]; bfr[nt][7] = hi[3];
        }
        #pragma unroll
        for (int mt = 0; mt < 4; ++mt) {
            const i32x4_t lo = *reinterpret_cast<const i32x4_t*>(Ak + mt * 16384);
            const i32x4_t hi = *reinterpret_cast<const i32x4_t*>(Ak + mt * 16384 + 16);
            i32x8_t af;
            af[0] = lo[0]; af[1] = lo[1]; af[2] = lo[2]; af[3] = lo[3];
            af[4] = hi[0]; af[5] = hi[1]; af[6] = hi[2]; af[7] = hi[3];
            #pragma unroll
            for (int nt = 0; nt < 4; ++nt)
                acc[mt][nt] = __builtin_amdgcn_mfma_scale_f32_16x16x128_f8f6f4(
                    af, bfr[nt], acc[mt][nt],
                    0, 0,                       // cbsz=fp8(e4m3), blgp=fp8(e4m3)
                    0, 0x7F7F7F7F,              // A scales: E8M0 127 = 2^0
                    0, 0x7F7F7F7F);             // B scales: 2^0
        }
    }

    // Epilogue: E = exp(S/TAU); acc holds 256*S -> exp2(acc / (256*TAU*ln2)).
    const float kScale = (float)(1.0 / (256.0 * 0.07 * 0.6931471805599453));
    float* rowslot = rowpart + (size_t)(blockIdx.x * 2 + (wave & 1)) * NB;
    float* colslot = colpart + (size_t)(blockIdx.y * 2 + (wave >> 1)) * NB;

    float csum[4] = {0.f, 0.f, 0.f, 0.f};
    #pragma unroll
    for (int mt = 0; mt < 4; ++mt) {
        float rsum[4] = {0.f, 0.f, 0.f, 0.f};
        #pragma unroll
        for (int nt = 0; nt < 4; ++nt) {
            #pragma unroll
            for (int r = 0; r < 4; ++r) {
                const float e = exp2f(acc[mt][nt][r] * kScale);
                rsum[r]  += e;
                csum[nt] += e;
            }
        }
        #pragma unroll
        for (int r = 0; r < 4; ++r) {
            float v = rsum[r];
            v += __shfl_xor(v, 1, 64);
            v += __shfl_xor(v, 2, 64);
            v += __shfl_xor(v, 4, 64);
            v += __shfl_xor(v, 8, 64);
            if (l15 == 0)
                rowslot[R0 + wRow + mt * 16 + q * 4 + r] = v;   // plain store
        }
    }
    #pragma unroll
    for (int nt = 0; nt < 4; ++nt) {
        float v = csum[nt];
        v += __shfl_xor(v, 16, 64);
        v += __shfl_xor(v, 32, 64);
        if (lane < 16)
            colslot[C0 + wCol + nt * 16 + l15] = v;             // plain store
    }
}

// ---------------------------------------------------------------------------
// Kernel 3: sum the 64 privatized partials per row/col, then
// loss = -1/(2B) [ (2/TAU)*sum(sdiag) - sum(log(rowsum+extra))
//                  - sum(log(colsum+extra)) ].
// Double accumulation for the grand total.
// ---------------------------------------------------------------------------
__global__ __launch_bounds__(1024) void finalize(
    const float* __restrict__ rowpart, const float* __restrict__ colpart,
    const float* __restrict__ sdiag, float* __restrict__ out)
{
    const float extra = (float)(NB * 1e-6 + 1e-6);
    double local = 0.0;
    for (int i = threadIdx.x; i < NB; i += 1024) {
        float rs = 0.f, cs = 0.f;
        #pragma unroll 8
        for (int s = 0; s < 64; ++s) {
            rs += rowpart[s * NB + i];
            cs += colpart[s * NB + i];
        }
        local += (double)sdiag[i] * (2.0 / 0.07)
               - (double)logf(rs + extra)
               - (double)logf(cs + extra);
    }
    #pragma unroll
    for (int off = 1; off < 64; off <<= 1)
        local += __shfl_xor(local, off, 64);
    __shared__ double dred[16];
    const int wave = threadIdx.x >> 6;
    if ((threadIdx.x & 63) == 0) dred[wave] = local;
    __syncthreads();
    if (threadIdx.x == 0) {
        double tot = 0.0;
        #pragma unroll
        for (int w = 0; w < 16; ++w) tot += dred[w];
        out[0] = (float)(tot * (-1.0 / (2.0 * NB)));
    }
}

// ---------------------------------------------------------------------------
extern "C" void kernel_launch(void* const* d_in, const int* in_sizes, int n_in,
                              void* d_out, int out_size, void* d_ws, size_t ws_size,
                              hipStream_t stream)
{
    const float* x = (const float*)d_in[0];
    const float* y = (const float*)d_in[1];
    float* out = (float*)d_out;

    char* ws = (char*)d_ws;
    unsigned char* xq = (unsigned char*)ws;                                 // 4 MB swizzled
    unsigned char* yq = (unsigned char*)(ws + (size_t)4 * 1024 * 1024);     // 4 MB swizzled
    float* rowpart = (float*)(ws + (size_t)8 * 1024 * 1024);                // 64*4096*4 = 1 MB
    float* colpart = (float*)(ws + (size_t)9 * 1024 * 1024);                // 1 MB
    float* sdiag   = (float*)(ws + (size_t)10 * 1024 * 1024);               // 16 KB

    normalize_rows<<<NB / 4, 256, 0, stream>>>(x, y, (unsigned*)xq, (unsigned*)yq,
                                               sdiag);

    dim3 grid(NB / 128, NB / 128);
    gemm_exp_sums<<<grid, 256, 0, stream>>>(xq, yq, rowpart, colpart);

    finalize<<<1, 1024, 0, stream>>>(rowpart, colpart, sdiag, out);
}

// Round 10
// 116.572 us; speedup vs baseline: 1.1121x; 1.1121x over previous
//
#include <hip/hip_runtime.h>
#include <hip/hip_bf16.h>

#define NB 4096
#define DK 1024           // elements per row (fp8 row = 1024 B)
#define EPSF 1e-6f
#define QSCALE 16.0f      // fp8 pre-scale (power of 2; cancelled exactly in exp)

typedef __attribute__((ext_vector_type(8))) int   i32x8_t;
typedef __attribute__((ext_vector_type(4))) int   i32x4_t;
typedef __attribute__((ext_vector_type(4))) float f32x4_t;

// ---------------------------------------------------------------------------
// Fragment-swizzled fp8 layout (both matrices): for row, k:
//   p = row>>4, r = row&15, kb = k>>7, q = (k>>5)&3, b = k&31
//   byte offset = (p*32 + kb*4 + q)*512 + r*32 + b
// Wave fragment (lane = q*16 + l15) for panel p, kb: 64 lanes x 32 contiguous
// bytes at (p*32+kb*4+q)*512 + l15*32. Proven absmax-0 since r5.
// ---------------------------------------------------------------------------

// ---------------------------------------------------------------------------
// Kernel 1: wave-per-row normalize -> fp8 e4m3 (x QSCALE) in swizzled layout.
// r10: lane-per-16B packing — lane l owns k in [16l,16l+16), packs 16 fp8
// bytes, ONE dwordx4 store per matrix (r7 did 4 scattered 4-B stores).
// Also zeroes rowsum/colsum (atomic epilogue restored) and exact fp32 diag.
// ---------------------------------------------------------------------------
__global__ __launch_bounds__(256) void normalize_rows(
    const float* __restrict__ x, const float* __restrict__ y,
    unsigned char* __restrict__ xq, unsigned char* __restrict__ yq,
    float* __restrict__ sdiag, float* __restrict__ zerobuf)
{
    const int t = threadIdx.x;
    const int gid = blockIdx.x * 256 + t;
    if (gid < 2 * NB) zerobuf[gid] = 0.f;   // rowsum+colsum contiguous

    const int wave = t >> 6;
    const int lane = t & 63;
    const int row  = blockIdx.x * 4 + wave;

    const float4* xr = reinterpret_cast<const float4*>(x + (size_t)row * DK);
    const float4* yr = reinterpret_cast<const float4*>(y + (size_t)row * DK);

    // lane l: k in [16l, 16l+16) -> float4s [4l .. 4l+3]
    float4 xv[4], yv[4];
    float ssx = 0.f, ssy = 0.f, sxy = 0.f;
    #pragma unroll
    for (int jj = 0; jj < 4; ++jj) {
        xv[jj] = xr[lane * 4 + jj];
        yv[jj] = yr[lane * 4 + jj];
        ssx += xv[jj].x*xv[jj].x + xv[jj].y*xv[jj].y + xv[jj].z*xv[jj].z + xv[jj].w*xv[jj].w;
        ssy += yv[jj].x*yv[jj].x + yv[jj].y*yv[jj].y + yv[jj].z*yv[jj].z + yv[jj].w*yv[jj].w;
        sxy += xv[jj].x*yv[jj].x + xv[jj].y*yv[jj].y + xv[jj].z*yv[jj].z + xv[jj].w*yv[jj].w;
    }
    #pragma unroll
    for (int off = 1; off < 64; off <<= 1) {
        ssx += __shfl_xor(ssx, off, 64);
        ssy += __shfl_xor(ssy, off, 64);
        sxy += __shfl_xor(sxy, off, 64);
    }
    const float invx = 1.0f / fmaxf(sqrtf(ssx), EPSF);
    const float invy = 1.0f / fmaxf(sqrtf(ssy), EPSF);
    const float sx = invx * QSCALE;
    const float sy = invy * QSCALE;

    // Pack 16 fp8 bytes per matrix (byte i of dword jj <-> k = 16l+4jj+i,
    // identical byte order to the proven r7 layout).
    i32x4_t xb, yb;
    #pragma unroll
    for (int jj = 0; jj < 4; ++jj) {
        int px = __builtin_amdgcn_cvt_pk_fp8_f32(xv[jj].x * sx, xv[jj].y * sx, 0, false);
        px     = __builtin_amdgcn_cvt_pk_fp8_f32(xv[jj].z * sx, xv[jj].w * sx, px, true);
        int py = __builtin_amdgcn_cvt_pk_fp8_f32(yv[jj].x * sy, yv[jj].y * sy, 0, false);
        py     = __builtin_amdgcn_cvt_pk_fp8_f32(yv[jj].z * sy, yv[jj].w * sy, py, true);
        xb[jj] = px;
        yb[jj] = py;
    }

    // Swizzled destination for k0 = 16l: kb=l>>3, q=(l>>1)&3, b=(l&1)*16.
    const int p = row >> 4, r = row & 15;
    const unsigned off = (unsigned)(p * 32 + (lane >> 3) * 4 + ((lane >> 1) & 3)) * 512
                       + r * 32 + (lane & 1) * 16;
    *reinterpret_cast<i32x4_t*>(xq + off) = xb;
    *reinterpret_cast<i32x4_t*>(yq + off) = yb;

    if (lane == 0) sdiag[row] = sxy * invx * invy;
}

// ---------------------------------------------------------------------------
// GEMM helpers
// ---------------------------------------------------------------------------
__device__ __forceinline__ i32x8_t ldfrag(const unsigned char* p) {
    const i32x4_t lo = *reinterpret_cast<const i32x4_t*>(p);
    const i32x4_t hi = *reinterpret_cast<const i32x4_t*>(p + 16);
    i32x8_t r;
    r[0] = lo[0]; r[1] = lo[1]; r[2] = lo[2]; r[3] = lo[3];
    r[4] = hi[0]; r[5] = hi[1]; r[6] = hi[2]; r[7] = hi[3];
    return r;
}

// ---------------------------------------------------------------------------
// Kernel 2: S' = 256 * xn*yn^T via MX-fp8 (unit scales), 128x128 tiles.
// r10 theory: the invariant ~40us is lockstep-wave latency serialization —
// co-resident waves run identical code, stall on the same multi-batch vmcnt
// waits (~5 per stage x ~900cyc L3). Fixes:
//  (a) ALL 8 fragments loaded up front per stage -> one vmcnt batch;
//  (b) phase-staggered K start: kb0=(2*wave+(bx&1))&7 — neighbors' MFMAs
//      cover this wave's load latency (kb-sum is order-invariant).
// Epilogue: r7's proven atomic row/col reduction (r9 cleared atomics of
// blame).
// ---------------------------------------------------------------------------
__global__ __launch_bounds__(256) void gemm_exp_sums(
    const unsigned char* __restrict__ xq, const unsigned char* __restrict__ yq,
    float* __restrict__ rowsum, float* __restrict__ colsum)
{
    const int t    = threadIdx.x;
    const int lane = t & 63;
    const int wave = t >> 6;
    const int q    = lane >> 4;    // quad: selects 32B k-chunk
    const int l15  = lane & 15;

    const int R0 = blockIdx.y * 128;
    const int C0 = blockIdx.x * 128;
    const int wRow = (wave >> 1) * 64;   // wave's 64x64 quadrant
    const int wCol = (wave & 1) * 64;

    f32x4_t acc[4][4];
    #pragma unroll
    for (int i = 0; i < 4; i++)
        #pragma unroll
        for (int j = 0; j < 4; j++)
            acc[i][j] = (f32x4_t){0.f, 0.f, 0.f, 0.f};

    // Panel bases; mt/nt step = 32*512 = 16384 B, kb step = 4*512 = 2048 B.
    const unsigned char* Abase =
        xq + (size_t)(((R0 + wRow) >> 4) * 32 + q) * 512 + l15 * 32;
    const unsigned char* Bbase =
        yq + (size_t)(((C0 + wCol) >> 4) * 32 + q) * 512 + l15 * 32;

    const int kb0 = (2 * wave + (blockIdx.x & 1)) & 7;   // phase stagger

    #pragma unroll 1
    for (int s = 0; s < 8; ++s) {
        const int kb = (kb0 + s) & 7;
        const unsigned char* Ak = Abase + kb * 2048;
        const unsigned char* Bk = Bbase + kb * 2048;

        i32x8_t bfr[4], afr[4];
        #pragma unroll
        for (int nt = 0; nt < 4; ++nt) bfr[nt] = ldfrag(Bk + nt * 16384);
        #pragma unroll
        for (int mt = 0; mt < 4; ++mt) afr[mt] = ldfrag(Ak + mt * 16384);

        #pragma unroll
        for (int mt = 0; mt < 4; ++mt)
            #pragma unroll
            for (int nt = 0; nt < 4; ++nt)
                acc[mt][nt] = __builtin_amdgcn_mfma_scale_f32_16x16x128_f8f6f4(
                    afr[mt], bfr[nt], acc[mt][nt],
                    0, 0,                       // cbsz=fp8(e4m3), blgp=fp8(e4m3)
                    0, 0x7F7F7F7F,              // A scales: E8M0 127 = 2^0
                    0, 0x7F7F7F7F);             // B scales: 2^0
    }

    // Epilogue: E = exp(S/TAU); acc holds 256*S -> exp2(acc / (256*TAU*ln2)).
    const float kScale = (float)(1.0 / (256.0 * 0.07 * 0.6931471805599453));
    float csum[4] = {0.f, 0.f, 0.f, 0.f};
    #pragma unroll
    for (int mt = 0; mt < 4; ++mt) {
        float rsum[4] = {0.f, 0.f, 0.f, 0.f};
        #pragma unroll
        for (int nt = 0; nt < 4; ++nt) {
            #pragma unroll
            for (int r = 0; r < 4; ++r) {
                const float e = exp2f(acc[mt][nt][r] * kScale);
                rsum[r]  += e;
                csum[nt] += e;
            }
        }
        #pragma unroll
        for (int r = 0; r < 4; ++r) {
            float v = rsum[r];
            v += __shfl_xor(v, 1, 64);
            v += __shfl_xor(v, 2, 64);
            v += __shfl_xor(v, 4, 64);
            v += __shfl_xor(v, 8, 64);
            if (l15 == 0)
                atomicAdd(&rowsum[R0 + wRow + mt * 16 + q * 4 + r], v);
        }
    }
    #pragma unroll
    for (int nt = 0; nt < 4; ++nt) {
        float v = csum[nt];
        v += __shfl_xor(v, 16, 64);
        v += __shfl_xor(v, 32, 64);
        if (lane < 16)
            atomicAdd(&colsum[C0 + wCol + nt * 16 + l15], v);
    }
}

// ---------------------------------------------------------------------------
// Kernel 3: loss = -1/(2B) [ (2/TAU)*sum(sdiag) - sum(log(rowsum+extra))
//                            - sum(log(colsum+extra)) ]   (r7's cheap version)
// ---------------------------------------------------------------------------
__global__ __launch_bounds__(1024) void finalize(
    const float* __restrict__ rowsum, const float* __restrict__ colsum,
    const float* __restrict__ sdiag, float* __restrict__ out)
{
    const float extra = (float)(NB * 1e-6 + 1e-6);
    double local = 0.0;
    for (int i = threadIdx.x; i < NB; i += 1024) {
        local += (double)sdiag[i] * (2.0 / 0.07)
               - (double)logf(rowsum[i] + extra)
               - (double)logf(colsum[i] + extra);
    }
    #pragma unroll
    for (int off = 1; off < 64; off <<= 1)
        local += __shfl_xor(local, off, 64);
    __shared__ double dred[16];
    const int wave = threadIdx.x >> 6;
    if ((threadIdx.x & 63) == 0) dred[wave] = local;
    __syncthreads();
    if (threadIdx.x == 0) {
        double tot = 0.0;
        #pragma unroll
        for (int w = 0; w < 16; ++w) tot += dred[w];
        out[0] = (float)(tot * (-1.0 / (2.0 * NB)));
    }
}

// ---------------------------------------------------------------------------
extern "C" void kernel_launch(void* const* d_in, const int* in_sizes, int n_in,
                              void* d_out, int out_size, void* d_ws, size_t ws_size,
                              hipStream_t stream)
{
    const float* x = (const float*)d_in[0];
    const float* y = (const float*)d_in[1];
    float* out = (float*)d_out;

    char* ws = (char*)d_ws;
    unsigned char* xq = (unsigned char*)ws;                                 // 4 MB swizzled
    unsigned char* yq = (unsigned char*)(ws + (size_t)4 * 1024 * 1024);     // 4 MB swizzled
    float* rowsum = (float*)(ws + (size_t)8 * 1024 * 1024);                 // 16 KB
    float* colsum = rowsum + NB;                                            // 16 KB
    float* sdiag  = colsum + NB;                                            // 16 KB

    normalize_rows<<<NB / 4, 256, 0, stream>>>(x, y, xq, yq, sdiag, rowsum);

    dim3 grid(NB / 128, NB / 128);
    gemm_exp_sums<<<grid, 256, 0, stream>>>(xq, yq, rowsum, colsum);

    finalize<<<1, 1024, 0, stream>>>(rowsum, colsum, sdiag, out);
}

// Round 11
// 107.395 us; speedup vs baseline: 1.2071x; 1.0855x over previous
//
#include <hip/hip_runtime.h>
#include <hip/hip_bf16.h>

#define NB 4096
#define DK 1024           // elements per row (fp8 row = 1024 B)
#define EPSF 1e-6f
#define QSCALE 16.0f      // fp8 pre-scale (power of 2; cancelled exactly in exp)

typedef __attribute__((ext_vector_type(8))) int   i32x8_t;
typedef __attribute__((ext_vector_type(4))) int   i32x4_t;
typedef __attribute__((ext_vector_type(4))) float f32x4_t;

// ---------------------------------------------------------------------------
// Global fp8 layout with the r6-proven LDS slot-swizzle BAKED IN.
// For row, k:  p=row>>4, r=row&15, kb=k>>7, s=(k>>4)&7 (16B slot), b=k&15:
//   byte offset = (p*32 + kb*4)*512 + r*128 + ((s ^ (r&7))<<4) + b
// A (p,kb) chunk is 2 KB contiguous; global_load_lds copies it verbatim, and
// the in-chunk layout is exactly r6's zero-conflict pattern (row stride
// 128 B, slot XOR row&7).
// ---------------------------------------------------------------------------

// async global->LDS, 16 B per lane. LDS dest is wave-uniform base + lane*16.
__device__ __forceinline__ void async16(const void* g, void* lds) {
    __builtin_amdgcn_global_load_lds(
        (const __attribute__((address_space(1))) void*)g,
        (__attribute__((address_space(3))) void*)lds, 16, 0, 0);
}

// ---------------------------------------------------------------------------
// Kernel 1: wave-per-row normalize -> fp8 e4m3 (x QSCALE) in the swizzled
// layout above; exact fp32 diagonal; zeroes rowsum/colsum.
// Lane l owns k in [16l,16l+16): kb=l>>3, slot=(l&7)^(r&7) -> one dwordx4
// store per matrix.
// ---------------------------------------------------------------------------
__global__ __launch_bounds__(256) void normalize_rows(
    const float* __restrict__ x, const float* __restrict__ y,
    unsigned char* __restrict__ xq, unsigned char* __restrict__ yq,
    float* __restrict__ sdiag, float* __restrict__ zerobuf)
{
    const int t = threadIdx.x;
    const int gid = blockIdx.x * 256 + t;
    if (gid < 2 * NB) zerobuf[gid] = 0.f;   // rowsum+colsum contiguous

    const int wave = t >> 6;
    const int lane = t & 63;
    const int row  = blockIdx.x * 4 + wave;

    const float4* xr = reinterpret_cast<const float4*>(x + (size_t)row * DK);
    const float4* yr = reinterpret_cast<const float4*>(y + (size_t)row * DK);

    float4 xv[4], yv[4];
    float ssx = 0.f, ssy = 0.f, sxy = 0.f;
    #pragma unroll
    for (int jj = 0; jj < 4; ++jj) {
        xv[jj] = xr[lane * 4 + jj];
        yv[jj] = yr[lane * 4 + jj];
        ssx += xv[jj].x*xv[jj].x + xv[jj].y*xv[jj].y + xv[jj].z*xv[jj].z + xv[jj].w*xv[jj].w;
        ssy += yv[jj].x*yv[jj].x + yv[jj].y*yv[jj].y + yv[jj].z*yv[jj].z + yv[jj].w*yv[jj].w;
        sxy += xv[jj].x*yv[jj].x + xv[jj].y*yv[jj].y + xv[jj].z*yv[jj].z + xv[jj].w*yv[jj].w;
    }
    #pragma unroll
    for (int off = 1; off < 64; off <<= 1) {
        ssx += __shfl_xor(ssx, off, 64);
        ssy += __shfl_xor(ssy, off, 64);
        sxy += __shfl_xor(sxy, off, 64);
    }
    const float invx = 1.0f / fmaxf(sqrtf(ssx), EPSF);
    const float invy = 1.0f / fmaxf(sqrtf(ssy), EPSF);
    const float sx = invx * QSCALE;
    const float sy = invy * QSCALE;

    i32x4_t xb, yb;
    #pragma unroll
    for (int jj = 0; jj < 4; ++jj) {
        int px = __builtin_amdgcn_cvt_pk_fp8_f32(xv[jj].x * sx, xv[jj].y * sx, 0, false);
        px     = __builtin_amdgcn_cvt_pk_fp8_f32(xv[jj].z * sx, xv[jj].w * sx, px, true);
        int py = __builtin_amdgcn_cvt_pk_fp8_f32(yv[jj].x * sy, yv[jj].y * sy, 0, false);
        py     = __builtin_amdgcn_cvt_pk_fp8_f32(yv[jj].z * sy, yv[jj].w * sy, py, true);
        xb[jj] = px;
        yb[jj] = py;
    }

    const int p = row >> 4, r = row & 15;
    const unsigned off = (unsigned)(p * 32 + (lane >> 3) * 4) * 512
                       + r * 128 + ((((lane & 7) ^ (r & 7))) << 4);
    *reinterpret_cast<i32x4_t*>(xq + off) = xb;
    *reinterpret_cast<i32x4_t*>(yq + off) = yb;

    if (lane == 0) sdiag[row] = sxy * invx * invy;
}

// ---------------------------------------------------------------------------
// Kernel 2: S' = 256 * xn*yn^T via MX-fp8, 256x256 tiles, 512 threads
// (8 waves; each wave computes two 64x64 quadrants: rows +0 and +128).
// Grid = 16x16 = 256 blocks = exactly 1/CU: single cohort, no tail.
// LDS: As/Bs 32 KB each (16 panels x 2 KB), staged per kb via
// global_load_lds (8 DMAs/wave/stage). Total staged bytes = 134 MB (half of
// the 128-tile scheme) -> 0.52 MB per CU, attacking the measured per-CU
// byte-rate wall. B fragments serve 32 MFMAs each.
// ---------------------------------------------------------------------------
__global__ __launch_bounds__(512) void gemm_exp_sums(
    const unsigned char* __restrict__ xq, const unsigned char* __restrict__ yq,
    float* __restrict__ rowsum, float* __restrict__ colsum)
{
    __shared__ __align__(16) unsigned char As[32 * 1024];  // 32 KB
    __shared__ __align__(16) unsigned char Bs[32 * 1024];  // 32 KB

    const int t    = threadIdx.x;
    const int lane = t & 63;
    const int wave = t >> 6;        // 0..7
    const int q    = lane >> 4;     // quad: selects 32B k-chunk (slots 2q,2q+1)
    const int l15  = lane & 15;

    const int R0 = blockIdx.y * 256;
    const int C0 = blockIdx.x * 256;
    const int wRow = (wave >> 2) * 64;   // 0 or 64 (second half at +128)
    const int wCol = (wave & 3) * 64;    // 0,64,128,192

    f32x4_t acc[2][4][4];
    #pragma unroll
    for (int hh = 0; hh < 2; hh++)
        #pragma unroll
        for (int i = 0; i < 4; i++)
            #pragma unroll
            for (int j = 0; j < 4; j++)
                acc[hh][i][j] = (f32x4_t){0.f, 0.f, 0.f, 0.f};

    // DMA sources: wave stages panels {wave, wave+8} of A and B.
    // Panel pa chunk for kb: global offset pa*16384 + kb*2048 (2 KB).
    const unsigned char* srcA =
        xq + (size_t)((R0 >> 4) + wave) * 16384 + lane * 16;
    const unsigned char* srcB =
        yq + (size_t)((C0 >> 4) + wave) * 16384 + lane * 16;

    // LDS read bases (r6 zero-conflict pattern): panel chunk + l15*128 +
    // slot*16, slot = (2q|h)^(l15&7).
    const int sLo = (((2 * q)    ) ^ (l15 & 7)) << 4;
    const int sHi = (((2 * q) + 1) ^ (l15 & 7)) << 4;

    #pragma unroll 1
    for (int kb = 0; kb < 8; ++kb) {
        __syncthreads();   // previous stage's reads done before overwrite
        #pragma unroll
        for (int h2 = 0; h2 < 2; ++h2) {
            async16(srcA + kb * 2048 + h2 * 1024,          &As[wave * 2048 + h2 * 1024]);
            async16(srcA + kb * 2048 + h2 * 1024 + 131072, &As[(wave + 8) * 2048 + h2 * 1024]);
            async16(srcB + kb * 2048 + h2 * 1024,          &Bs[wave * 2048 + h2 * 1024]);
            async16(srcB + kb * 2048 + h2 * 1024 + 131072, &Bs[(wave + 8) * 2048 + h2 * 1024]);
        }
        __syncthreads();   // compiler inserts vmcnt(0) drain before this

        i32x8_t bfr[4];
        #pragma unroll
        for (int nt = 0; nt < 4; ++nt) {
            const unsigned char* c = &Bs[((wCol >> 4) + nt) * 2048 + l15 * 128];
            const i32x4_t lo = *reinterpret_cast<const i32x4_t*>(c + sLo);
            const i32x4_t hi = *reinterpret_cast<const i32x4_t*>(c + sHi);
            bfr[nt][0] = lo[0]; bfr[nt][1] = lo[1]; bfr[nt][2] = lo[2]; bfr[nt][3] = lo[3];
            bfr[nt][4] = hi[0]; bfr[nt][5] = hi[1]; bfr[nt][6] = hi[2]; bfr[nt][7] = hi[3];
        }
        #pragma unroll
        for (int hh = 0; hh < 2; ++hh) {
            #pragma unroll
            for (int mt = 0; mt < 4; ++mt) {
                const unsigned char* c =
                    &As[((wRow >> 4) + hh * 8 + mt) * 2048 + l15 * 128];
                const i32x4_t lo = *reinterpret_cast<const i32x4_t*>(c + sLo);
                const i32x4_t hi = *reinterpret_cast<const i32x4_t*>(c + sHi);
                i32x8_t af;
                af[0] = lo[0]; af[1] = lo[1]; af[2] = lo[2]; af[3] = lo[3];
                af[4] = hi[0]; af[5] = hi[1]; af[6] = hi[2]; af[7] = hi[3];
                #pragma unroll
                for (int nt = 0; nt < 4; ++nt)
                    acc[hh][mt][nt] = __builtin_amdgcn_mfma_scale_f32_16x16x128_f8f6f4(
                        af, bfr[nt], acc[hh][mt][nt],
                        0, 0,                       // cbsz/blgp = fp8 e4m3
                        0, 0x7F7F7F7F,              // A scales: 2^0
                        0, 0x7F7F7F7F);             // B scales: 2^0
            }
        }
    }

    // Epilogue: E = exp(S/TAU); acc holds 256*S -> exp2(acc / (256*TAU*ln2)).
    const float kScale = (float)(1.0 / (256.0 * 0.07 * 0.6931471805599453));
    float csum[4] = {0.f, 0.f, 0.f, 0.f};
    #pragma unroll
    for (int hh = 0; hh < 2; ++hh) {
        #pragma unroll
        for (int mt = 0; mt < 4; ++mt) {
            float rsum[4] = {0.f, 0.f, 0.f, 0.f};
            #pragma unroll
            for (int nt = 0; nt < 4; ++nt) {
                #pragma unroll
                for (int r = 0; r < 4; ++r) {
                    const float e = exp2f(acc[hh][mt][nt][r] * kScale);
                    rsum[r]  += e;
                    csum[nt] += e;
                }
            }
            #pragma unroll
            for (int r = 0; r < 4; ++r) {
                float v = rsum[r];
                v += __shfl_xor(v, 1, 64);
                v += __shfl_xor(v, 2, 64);
                v += __shfl_xor(v, 4, 64);
                v += __shfl_xor(v, 8, 64);
                if (l15 == 0)
                    atomicAdd(&rowsum[R0 + wRow + hh * 128 + mt * 16 + q * 4 + r], v);
            }
        }
    }
    #pragma unroll
    for (int nt = 0; nt < 4; ++nt) {
        float v = csum[nt];
        v += __shfl_xor(v, 16, 64);
        v += __shfl_xor(v, 32, 64);
        if (lane < 16)
            atomicAdd(&colsum[C0 + wCol + nt * 16 + l15], v);
    }
}

// ---------------------------------------------------------------------------
// Kernel 3: loss = -1/(2B) [ (2/TAU)*sum(sdiag) - sum(log(rowsum+extra))
//                            - sum(log(colsum+extra)) ]
// ---------------------------------------------------------------------------
__global__ __launch_bounds__(1024) void finalize(
    const float* __restrict__ rowsum, const float* __restrict__ colsum,
    const float* __restrict__ sdiag, float* __restrict__ out)
{
    const float extra = (float)(NB * 1e-6 + 1e-6);
    double local = 0.0;
    for (int i = threadIdx.x; i < NB; i += 1024) {
        local += (double)sdiag[i] * (2.0 / 0.07)
               - (double)logf(rowsum[i] + extra)
               - (double)logf(colsum[i] + extra);
    }
    #pragma unroll
    for (int off = 1; off < 64; off <<= 1)
        local += __shfl_xor(local, off, 64);
    __shared__ double dred[16];
    const int wave = threadIdx.x >> 6;
    if ((threadIdx.x & 63) == 0) dred[wave] = local;
    __syncthreads();
    if (threadIdx.x == 0) {
        double tot = 0.0;
        #pragma unroll
        for (int w = 0; w < 16; ++w) tot += dred[w];
        out[0] = (float)(tot * (-1.0 / (2.0 * NB)));
    }
}

// ---------------------------------------------------------------------------
extern "C" void kernel_launch(void* const* d_in, const int* in_sizes, int n_in,
                              void* d_out, int out_size, void* d_ws, size_t ws_size,
                              hipStream_t stream)
{
    const float* x = (const float*)d_in[0];
    const float* y = (const float*)d_in[1];
    float* out = (float*)d_out;

    char* ws = (char*)d_ws;
    unsigned char* xq = (unsigned char*)ws;                                 // 4 MB swizzled
    unsigned char* yq = (unsigned char*)(ws + (size_t)4 * 1024 * 1024);     // 4 MB swizzled
    float* rowsum = (float*)(ws + (size_t)8 * 1024 * 1024);                 // 16 KB
    float* colsum = rowsum + NB;                                            // 16 KB
    float* sdiag  = colsum + NB;                                            // 16 KB

    normalize_rows<<<NB / 4, 256, 0, stream>>>(x, y, xq, yq, sdiag, rowsum);

    dim3 grid(16, 16);
    gemm_exp_sums<<<grid, 512, 0, stream>>>(xq, yq, rowsum, colsum);

    finalize<<<1, 1024, 0, stream>>>(rowsum, colsum, sdiag, out);
}